// Round 4
// baseline (285.722 us; speedup 1.0000x reference)
//
#include <hip/hip_runtime.h>

#define Bdim 64
#define Tdim 2048
#define Fdim 256
#define TAIL 256      // truncated EMA window: 0.8^256 ~ 1e-25, far below fp32 noise
#define NCH 8
#define CHT 32        // TAIL / NCH

#define BK 32         // 8 K-chunks of 32
#define NCHUNK 8      // Fdim / BK
#define PFD 2         // A register-prefetch depth (chunks in flight)

typedef __bf16 bf16x8 __attribute__((ext_vector_type(8)));
typedef float f32x16 __attribute__((ext_vector_type(16)));
typedef unsigned short u16x8 __attribute__((ext_vector_type(8)));

__device__ __forceinline__ unsigned short bf16_rne(float f) {
  unsigned int u = __float_as_uint(f);
  u += 0x7FFFu + ((u >> 16) & 1u);
  return (unsigned short)(u >> 16);
}

// Merged prep:
//  blocks [0,256):   W fp32 -> Wf bf16 in FRAGMENT order, n-subtile granular:
//    o = ((c*2 + s)*8 + nsub)*512 + lane*8 + e  holds bf16(W[k][n]) with
//    n = nsub*32 + (lane&31),  k = c*32 + (2*s + (lane>>5))*8 + e.
//    => every gemm B-fragment load is a coalesced 16B/lane dwordx4 stream.
//  blocks [256,768): EMA partial sums over t-chunks.
__global__ void prep(const float* __restrict__ x, const float* __restrict__ W,
                     unsigned short* __restrict__ Wf, float* __restrict__ part) {
  int blk = blockIdx.x;
  if (blk < Fdim) {
    int o = blk * 256 + threadIdx.x;
    int e = o & 7, lane = (o >> 3) & 63, nsub = (o >> 9) & 7, s = (o >> 12) & 1;
    int c = o >> 13;
    int n = nsub * 32 + (lane & 31);
    int k = c * 32 + (2 * s + (lane >> 5)) * 8 + e;
    Wf[o] = bf16_rne(W[k * Fdim + n]);
  } else {
    int j = blk - Fdim;                // 0..511
    int b = j & 63, c = j >> 6;
    int f = threadIdx.x;
    int t0 = Tdim - TAIL + c * CHT;
    // w(t) = 0.2 * 0.8^(T-1-t); iterate upward multiplying by 1.25 (exact in fp32)
    float w = 0.2f * exp2f((float)(Tdim - 1 - t0) * -0.32192809488736235f);
    const float* xp = x + ((size_t)b * Tdim + t0) * Fdim + f;
    float s = 0.f;
#pragma unroll
    for (int q = 0; q < CHT; ++q) {
      s += w * xp[(size_t)q * Fdim];
      w *= 1.25f;
    }
    part[(c * Bdim + b) * Fdim + f] = s;
  }
}

// out[row][n] = sum_k x[row][k]*W[k][n] + bias[n] + lastref[b][n]
// BARRIER-FREE per-wave GEMM: each wave independently computes a
// 32-row x 128-col output tile (block = 4 waves = 2m x 2n over 64 rows x 256 cols).
//  - A fragments gathered DIRECTLY from x: per (chunk,s) one contiguous 32B/lane
//    read (rows via lane&31, k-halves via lane>>5); the 4 loads per chunk fully
//    consume each 128B x-line; sibling n-wave re-hits L1. Reg-prefetch PFD chunks.
//  - B fragments streamed from Wf (fragment order, coalesced 16B/lane, L2-hot),
//    refilled immediately after use (one-chunk latency gap).
//  - NO loop barriers, NO loop LDS => compiler emits counted vmcnt, waves never
//    gang-stall on a vmcnt(0) drain (the m97-structure stall that capped rounds 0-3).
__global__ __launch_bounds__(256, 3)
void gemm_fused(const float* __restrict__ x, const unsigned short* __restrict__ Wf,
                const float* __restrict__ bias, const float* __restrict__ part,
                float* __restrict__ out) {
  __shared__ float lref[Fdim];                     // 1 KB total LDS

  const int tid = threadIdx.x;
  const int blk = blockIdx.x;            // 0..2047
  const int b = blk >> 5;                // 32 row-tiles per batch
  const size_t row0 = (size_t)blk * 64;

  const int wave = tid >> 6;
  const int mw = wave >> 1;              // m-subtile (32 rows)
  const int nw = wave & 1;               // n-half (128 cols)
  const int lane = tid & 63;
  const int lm = lane & 31;
  const int half = lane >> 5;

  {  // lastref[b][n] + bias[n], one n per thread
    float s = bias[tid];
#pragma unroll
    for (int c = 0; c < NCH; ++c) s += part[(c * Bdim + b) * Fdim + tid];
    lref[tid] = s;
  }
  __syncthreads();                       // the ONLY barrier

  // per-lane A row base; frag (c,s): 8 floats at col c*32 + (2s+half)*8
  const float* ax = x + (row0 + mw * 32 + lm) * Fdim;
  // B fragment stream base: frag (c,s,j) at bx + ((c*2+s)*8 + j)*512
  const unsigned short* bx = Wf + (size_t)(nw * 4) * 512 + lane * 8;

  f32x16 acc[4] = {};          // 4 n-subtiles of 32x32
  float4 Ar[PFD][2][2];        // raw A floats, [slot][s][lo/hi float4]
  bf16x8 Bf[2][4];             // current chunk's B fragments [s][j]

  // ---- prologue: issue A chunks 0..PFD-1 and B chunk 0 ----
#pragma unroll
  for (int p = 0; p < PFD; ++p) {
#pragma unroll
    for (int s = 0; s < 2; ++s) {
      const float* sp = ax + p * BK + (2 * s + half) * 8;
      Ar[p][s][0] = *(const float4*)sp;
      Ar[p][s][1] = *(const float4*)(sp + 4);
    }
  }
#pragma unroll
  for (int s = 0; s < 2; ++s)
#pragma unroll
    for (int j = 0; j < 4; ++j)
      Bf[s][j] = *(const bf16x8*)(bx + (size_t)(s * 8 + j) * 512);

  // ---- main loop: fully unrolled, barrier-free ----
#pragma unroll
  for (int c = 0; c < NCHUNK; ++c) {
    const int slot = c % PFD;
#pragma unroll
    for (int s = 0; s < 2; ++s) {
      float4 v0 = Ar[slot][s][0], v1 = Ar[slot][s][1];
      u16x8 w;
      w[0] = bf16_rne(v0.x); w[1] = bf16_rne(v0.y);
      w[2] = bf16_rne(v0.z); w[3] = bf16_rne(v0.w);
      w[4] = bf16_rne(v1.x); w[5] = bf16_rne(v1.y);
      w[6] = bf16_rne(v1.z); w[7] = bf16_rne(v1.w);
      bf16x8 af;
      *(u16x8*)&af = w;
      acc[0] = __builtin_amdgcn_mfma_f32_32x32x16_bf16(af, Bf[s][0], acc[0], 0, 0, 0);
      acc[1] = __builtin_amdgcn_mfma_f32_32x32x16_bf16(af, Bf[s][1], acc[1], 0, 0, 0);
      acc[2] = __builtin_amdgcn_mfma_f32_32x32x16_bf16(af, Bf[s][2], acc[2], 0, 0, 0);
      acc[3] = __builtin_amdgcn_mfma_f32_32x32x16_bf16(af, Bf[s][3], acc[3], 0, 0, 0);
      if (c + 1 < NCHUNK) {              // refill Bf[s] for chunk c+1 (after use)
#pragma unroll
        for (int j = 0; j < 4; ++j)
          Bf[s][j] = *(const bf16x8*)(bx + (size_t)(((c + 1) * 2 + s) * 8 + j) * 512);
      }
    }
    if (c + PFD < NCHUNK) {              // reissue A into freed slot
#pragma unroll
      for (int s = 0; s < 2; ++s) {
        const float* sp = ax + (c + PFD) * BK + (2 * s + half) * 8;
        Ar[slot][s][0] = *(const float4*)sp;
        Ar[slot][s][1] = *(const float4*)(sp + 4);
      }
    }
  }

  // epilogue: C/D layout col=lane&31, row=(r&3)+8*(r>>2)+4*(lane>>5)  [m74/m101]
  float* op = out + (row0 + mw * 32) * Fdim + nw * 128;
  const int rbase = 4 * half;
#pragma unroll
  for (int j = 0; j < 4; ++j) {
    float lb = lref[nw * 128 + j * 32 + lm];
#pragma unroll
    for (int r = 0; r < 16; ++r) {
      int rowi = (r & 3) + 8 * (r >> 2) + rbase;
      op[(size_t)rowi * Fdim + j * 32 + lm] = acc[j][r] + lb;
    }
  }
}

extern "C" void kernel_launch(void* const* d_in, const int* in_sizes, int n_in,
                              void* d_out, int out_size, void* d_ws, size_t ws_size,
                              hipStream_t stream) {
  const float* x = (const float*)d_in[0];
  const float* W = (const float*)d_in[1];
  const float* bias = (const float*)d_in[2];
  float* out = (float*)d_out;

  unsigned short* Wf = (unsigned short*)d_ws;                                    // 128 KB
  float* part = (float*)((char*)d_ws + Fdim * Fdim * sizeof(unsigned short));    // 512 KB

  prep<<<Fdim + Bdim * NCH, 256, 0, stream>>>(x, W, Wf, part);
  gemm_fused<<<(Bdim * Tdim) / 64, 256, 0, stream>>>(x, Wf, bias, part, out);
}

// Round 5
// 243.092 us; speedup vs baseline: 1.1754x; 1.1754x over previous
//
#include <hip/hip_runtime.h>

#define Bdim 64
#define Tdim 2048
#define Fdim 256
#define TAIL 256      // truncated EMA window: 0.8^256 ~ 1e-25, far below fp32 noise
#define NCH 8
#define CHT 32        // TAIL / NCH

#define NCHUNK 8      // Fdim / 32
#define FR_STR 520    // fragment stride in ushorts: 1024B + 16B pad (bank-group shift)

typedef __bf16 bf16x8 __attribute__((ext_vector_type(8)));
typedef float f32x16 __attribute__((ext_vector_type(16)));
typedef unsigned short u16x8 __attribute__((ext_vector_type(8)));

__device__ __forceinline__ unsigned short bf16_rne(float f) {
  unsigned int u = __float_as_uint(f);
  u += 0x7FFFu + ((u >> 16) & 1u);
  return (unsigned short)(u >> 16);
}

// Merged prep (identical to the round-3 verified version):
//  blocks [0,256):   W fp32 -> Wf bf16 in FRAGMENT order:
//    o = (w*32 + c*4 + s*2 + which)*512 + lane*8 + e  holds bf16(W[k][n]) with
//    n = w*64 + which*32 + (lane&31),  k = c*32 + (2*s + (lane>>5))*8 + e.
//  blocks [256,768): EMA partial sums over t-chunks.
__global__ void prep(const float* __restrict__ x, const float* __restrict__ W,
                     unsigned short* __restrict__ Wf, float* __restrict__ part) {
  int blk = blockIdx.x;
  if (blk < Fdim) {
    int o = blk * 256 + threadIdx.x;
    int e = o & 7, lane = (o >> 3) & 63, wh = (o >> 9) & 1, s = (o >> 10) & 1;
    int c = (o >> 11) & 7, w = o >> 14;
    int n = w * 64 + wh * 32 + (lane & 31);
    int k = c * 32 + (2 * s + (lane >> 5)) * 8 + e;
    Wf[o] = bf16_rne(W[k * Fdim + n]);
  } else {
    int j = blk - Fdim;                // 0..511
    int b = j & 63, c = j >> 6;
    int f = threadIdx.x;
    int t0 = Tdim - TAIL + c * CHT;
    float w = 0.2f * exp2f((float)(Tdim - 1 - t0) * -0.32192809488736235f);
    const float* xp = x + ((size_t)b * Tdim + t0) * Fdim + f;
    float s = 0.f;
#pragma unroll
    for (int q = 0; q < CHT; ++q) {
      s += w * xp[(size_t)q * Fdim];
      w *= 1.25f;
    }
    part[(c * Bdim + b) * Fdim + f] = s;
  }
}

// out[row][n] = sum_k x[row][k]*W[k][n] + bias[n] + lastref[b][n]
// ONE barrier per block:
//  1) stage whole 64x256 A tile: thread t -> row t>>2, 8 contiguous-32B granules
//     (gi = p*4 + (t&3)); fully coalesced, 16 dwordx4 in flight per thread.
//  2) cvt fp32->bf16, write to fragment-ordered LDS: frag f=(c,i,s) is 1KB,
//     dest index pos(dl)=dl^((dl>>5)<<2), frag stride 1040B. Both ds_write_b128
//     and ds_read_b128 hit exactly 4 lanes per 4-bank group (the b128 floor).
//  3) __syncthreads (the ONLY barrier).
//  4) fully-unrolled barrier-free K-loop: 4 ds_read + 8 MFMA per chunk;
//     B fragments streamed direct from Wf (L2-hot) with 2-chunk refill distance.
__global__ __launch_bounds__(256, 3)
void gemm_fused(const float* __restrict__ x, const unsigned short* __restrict__ Wf,
                const float* __restrict__ bias, const float* __restrict__ part,
                float* __restrict__ out) {
  __shared__ unsigned short Afrag[32 * FR_STR];    // 32 frags x 1040B = 33280 B
  __shared__ float lref[Fdim];                     // + 1 KB

  const int tid = threadIdx.x;
  const int blk = blockIdx.x;            // 0..2047
  const int b = blk >> 5;                // 32 row-tiles per batch
  const size_t row0 = (size_t)blk * 64;

  const int wave = tid >> 6;             // wave covers all 64 rows x 64 cols (n-slice)
  const int lane = tid & 63;
  const int lm = lane & 31;
  const int half = lane >> 5;

  // ---- A stage: row r = tid>>2, q = tid&3; granule gi = p*4+q, col = gi*8 ----
  const int r = tid >> 2, q = tid & 3;
  const int iw = r >> 5;                 // m-subtile this thread writes
  const int sq = q >> 1, hb = q & 1;     // k-sub-step, k-half
  const int dl = hb * 32 + (r & 31);     // destination MFMA lane
  const int wpos = dl ^ ((dl >> 5) << 2);
  const float* ap = x + (row0 + r) * Fdim + q * 8;

  float4 av[8][2];
#pragma unroll
  for (int p = 0; p < 8; ++p) {          // 16 loads issued back-to-back (MLP)
    av[p][0] = *(const float4*)(ap + p * 32);
    av[p][1] = *(const float4*)(ap + p * 32 + 4);
  }

  // lastref[b][n] + bias[n] (loads overlap the A loads)
  {
    float s = bias[tid];
#pragma unroll
    for (int c = 0; c < NCH; ++c) s += part[(c * Bdim + b) * Fdim + tid];
    lref[tid] = s;
  }

#pragma unroll
  for (int p = 0; p < 8; ++p) {          // cvt + fragment-order LDS write
    float4 v0 = av[p][0], v1 = av[p][1];
    u16x8 w;
    w[0] = bf16_rne(v0.x); w[1] = bf16_rne(v0.y);
    w[2] = bf16_rne(v0.z); w[3] = bf16_rne(v0.w);
    w[4] = bf16_rne(v1.x); w[5] = bf16_rne(v1.y);
    w[6] = bf16_rne(v1.z); w[7] = bf16_rne(v1.w);
    const int fragidx = (p * 2 + iw) * 2 + sq;
    *(u16x8*)&Afrag[fragidx * FR_STR + wpos * 8] = w;
  }
  __syncthreads();                       // the ONLY barrier

  // ---- K-loop: barrier-free, fully unrolled ----
  const unsigned short* bx = Wf + (size_t)wave * (32 * 512) + lane * 8;
  const int rpos = lane ^ ((lane >> 5) << 2);
  const unsigned short* abase = &Afrag[rpos * 8];

  f32x16 acc[2][2] = {};                 // [m-subtile][n-subtile]
  bf16x8 Bf[2][2][2];                    // [chunk parity][s][which]

#pragma unroll
  for (int cc = 0; cc < 2; ++cc)         // B chunks 0,1 in flight
#pragma unroll
    for (int s = 0; s < 2; ++s)
#pragma unroll
      for (int wh = 0; wh < 2; ++wh)
        Bf[cc][s][wh] = *(const bf16x8*)(bx + (size_t)(cc * 4 + s * 2 + wh) * 512);

#pragma unroll
  for (int c = 0; c < NCHUNK; ++c) {
    const int par = c & 1;
#pragma unroll
    for (int s = 0; s < 2; ++s) {
      bf16x8 a0 = *(const bf16x8*)&abase[((c * 2 + 0) * 2 + s) * FR_STR];
      bf16x8 a1 = *(const bf16x8*)&abase[((c * 2 + 1) * 2 + s) * FR_STR];
      acc[0][0] = __builtin_amdgcn_mfma_f32_32x32x16_bf16(a0, Bf[par][s][0], acc[0][0], 0, 0, 0);
      acc[0][1] = __builtin_amdgcn_mfma_f32_32x32x16_bf16(a0, Bf[par][s][1], acc[0][1], 0, 0, 0);
      acc[1][0] = __builtin_amdgcn_mfma_f32_32x32x16_bf16(a1, Bf[par][s][0], acc[1][0], 0, 0, 0);
      acc[1][1] = __builtin_amdgcn_mfma_f32_32x32x16_bf16(a1, Bf[par][s][1], acc[1][1], 0, 0, 0);
    }
    if (c + 2 < NCHUNK) {                // refill freed parity with chunk c+2
#pragma unroll
      for (int s = 0; s < 2; ++s)
#pragma unroll
        for (int wh = 0; wh < 2; ++wh)
          Bf[par][s][wh] =
              *(const bf16x8*)(bx + (size_t)((c + 2) * 4 + s * 2 + wh) * 512);
    }
  }

  // epilogue: C/D layout col=lane&31, row=(r&3)+8*(r>>2)+4*(lane>>5)  [m74/m101]
  float* op = out + row0 * Fdim;
  const int rbase = 4 * half;
#pragma unroll
  for (int i = 0; i < 2; ++i) {
#pragma unroll
    for (int j = 0; j < 2; ++j) {
      int n = wave * 64 + j * 32 + lm;
      float lb = lref[n];
#pragma unroll
      for (int rr = 0; rr < 16; ++rr) {
        int rowi = i * 32 + (rr & 3) + 8 * (rr >> 2) + rbase;
        op[(size_t)rowi * Fdim + n] = acc[i][j][rr] + lb;
      }
    }
  }
}

extern "C" void kernel_launch(void* const* d_in, const int* in_sizes, int n_in,
                              void* d_out, int out_size, void* d_ws, size_t ws_size,
                              hipStream_t stream) {
  const float* x = (const float*)d_in[0];
  const float* W = (const float*)d_in[1];
  const float* bias = (const float*)d_in[2];
  float* out = (float*)d_out;

  unsigned short* Wf = (unsigned short*)d_ws;                                    // 128 KB
  float* part = (float*)((char*)d_ws + Fdim * Fdim * sizeof(unsigned short));    // 512 KB

  prep<<<Fdim + Bdim * NCH, 256, 0, stream>>>(x, W, Wf, part);
  gemm_fused<<<(Bdim * Tdim) / 64, 256, 0, stream>>>(x, Wf, bias, part, out);
}